// Round 1
// baseline (92.687 us; speedup 1.0000x reference)
//
#include <hip/hip_runtime.h>
#include <hip/hip_bf16.h>
#include <cstdint>
#include <cstddef>

#define PI_F 3.14159265358979323846f
#define TWO_PI_F 6.28318530717958647692f

typedef __bf16 bf16x8 __attribute__((ext_vector_type(8)));
typedef __bf16 bf16x4 __attribute__((ext_vector_type(4)));
typedef float  f32x4  __attribute__((ext_vector_type(4)));

__device__ __forceinline__ __bf16 to_bf16(float f) { return (__bf16)f; }

// ---------------------------------------------------------------------------
// Kernel P: per-(layer,pair) beamsplitter params -> ws table.
// t4[idx] = (Re(e*c), Im(e*c), Re(e*s), Im(e*s)), t2[idx] = (c, s)
// after the reference's normalization (theta%pi, flip past pi/2, phi mod 2pi).
// ---------------------------------------------------------------------------
__global__ __launch_bounds__(256) void olk_params(
    const float* __restrict__ theta, const float* __restrict__ phi,
    float4* __restrict__ t4, float2* __restrict__ t2) {
  int idx = blockIdx.x * 256 + threadIdx.x;  // 256*128 = 32768 total
  float t = fmodf(theta[idx], PI_F);
  float p = phi[idx];
  if (t > 0.5f * PI_F) { t = PI_F - t; p += PI_F; }
  p = fmodf(p, TWO_PI_F);
  float c  = cosf(t), s  = sinf(t);
  float cp = cosf(p), sp = sinf(p);
  t4[idx] = make_float4(cp * c, sp * c, cp * s, sp * s);
  t2[idx] = make_float2(c, s);
}

// ---------------------------------------------------------------------------
// Build kernel: V = e_r^T, then V <- V * T_l for l = 255..0.
// One wave per output row r (64 waves = 16 blocks x 4 waves).
// Lane owns columns 4*lane .. 4*lane+3 (4 complex values in registers).
// Even layer pairs (2p,2p+1): fully lane-local.
// Odd  layer pairs (2p+1,2p+2): one boundary pair per lane -> 6 shuffles.
// Column update for pair (m1,m2):
//   new[:,m1] = (e c) V[:,m1] + (e s) V[:,m2];  new[:,m2] = -s V[:,m1] + c V[:,m2]
// ---------------------------------------------------------------------------
struct P8 {           // params for 8 consecutive layers (fully static indexing)
  float4 qa[8];       // pair 2*lane   : (ec_re, ec_im, es_re, es_im)
  float4 qb[8];       // pair 2*lane+1 : same
  float4 cc[8];       // (c_a, s_a, c_b, s_b)
};

template<bool TBL>
__device__ __forceinline__ void loadP8(P8& P, int lb, int lane,
    const float4* __restrict__ t4, const float2* __restrict__ t2,
    const float* __restrict__ theta, const float* __restrict__ phi) {
  if (TBL) {
#pragma unroll
    for (int k = 0; k < 8; ++k) {
      int idx = (lb + k) * 128 + 2 * lane;
      P.qa[k] = t4[idx];
      P.qb[k] = t4[idx + 1];
      P.cc[k] = *(const float4*)&t2[idx];   // idx even -> 16B aligned
    }
  } else {
#pragma unroll
    for (int k = 0; k < 8; ++k) {
      int idx = (lb + k) * 128 + 2 * lane;
      float2 th = *(const float2*)&theta[idx];
      float2 ph = *(const float2*)&phi[idx];
      float ta = fmodf(th.x, PI_F), pa = ph.x;
      if (ta > 0.5f * PI_F) { ta = PI_F - ta; pa += PI_F; }
      pa = fmodf(pa, TWO_PI_F);
      float tb = fmodf(th.y, PI_F), pb = ph.y;
      if (tb > 0.5f * PI_F) { tb = PI_F - tb; pb += PI_F; }
      pb = fmodf(pb, TWO_PI_F);
      float ca = cosf(ta), sa = sinf(ta), cpa = cosf(pa), spa = sinf(pa);
      float cb = cosf(tb), sb = sinf(tb), cpb = cosf(pb), spb = sinf(pb);
      P.qa[k] = make_float4(cpa * ca, spa * ca, cpa * sa, spa * sa);
      P.qb[k] = make_float4(cpb * cb, spb * cb, cpb * sb, spb * sb);
      P.cc[k] = make_float4(ca, sa, cb, sb);
    }
  }
}

__device__ __forceinline__ void layer_step(bool odd, int lane,
    float4 qa, float4 qb, float4 cc,
    float& vre0, float& vim0, float& vre1, float& vim1,
    float& vre2, float& vim2, float& vre3, float& vim3) {
  if (!odd) {
    // pair a on (c0,c1), pair b on (c2,c3) — all local
    float nr0 = qa.x * vre0 - qa.y * vim0 + qa.z * vre1 - qa.w * vim1;
    float ni0 = qa.x * vim0 + qa.y * vre0 + qa.z * vim1 + qa.w * vre1;
    float nr1 = cc.x * vre1 - cc.y * vre0;
    float ni1 = cc.x * vim1 - cc.y * vim0;
    float nr2 = qb.x * vre2 - qb.y * vim2 + qb.z * vre3 - qb.w * vim3;
    float ni2 = qb.x * vim2 + qb.y * vre2 + qb.z * vim3 + qb.w * vre3;
    float nr3 = cc.z * vre3 - cc.w * vre2;
    float ni3 = cc.z * vim3 - cc.w * vim2;
    vre0 = nr0; vim0 = ni0; vre1 = nr1; vim1 = ni1;
    vre2 = nr2; vim2 = ni2; vre3 = nr3; vim3 = ni3;
  } else {
    int nxt = (lane + 1) & 63, prv = (lane + 63) & 63;
    float xre = __shfl(vre0, nxt, 64);   // next lane's col0 (pre-update)
    float xim = __shfl(vim0, nxt, 64);
    float pre = __shfl(vre3, prv, 64);   // prev lane's col3 (pre-update)
    float pim = __shfl(vim3, prv, 64);
    float cp  = __shfl(cc.z, prv, 64);   // prev lane's pair-b (c,s)
    float sp  = __shfl(cc.w, prv, 64);
    // pair a on (c1,c2) — local
    float nr1 = qa.x * vre1 - qa.y * vim1 + qa.z * vre2 - qa.w * vim2;
    float ni1 = qa.x * vim1 + qa.y * vre1 + qa.z * vim2 + qa.w * vre2;
    float nr2 = cc.x * vre2 - cc.y * vre1;
    float ni2 = cc.x * vim2 - cc.y * vim1;
    // pair b m1 side on c3, m2 is next lane's c0
    float nr3 = qb.x * vre3 - qb.y * vim3 + qb.z * xre - qb.w * xim;
    float ni3 = qb.x * vim3 + qb.y * vre3 + qb.z * xim + qb.w * xre;
    // previous lane's pair-b m2 side on our c0, m1 is prev lane's c3
    float nr0 = cp * vre0 - sp * pre;
    float ni0 = cp * vim0 - sp * pim;
    vre0 = nr0; vim0 = ni0; vre1 = nr1; vim1 = ni1;
    vre2 = nr2; vim2 = ni2; vre3 = nr3; vim3 = ni3;
  }
}

template<bool TBL>
__global__ __launch_bounds__(256) void olk_build(
    const float* __restrict__ theta, const float* __restrict__ phi,
    const float* __restrict__ outph,
    const float4* __restrict__ t4, const float2* __restrict__ t2,
    __bf16* __restrict__ Tb) {
  int lane = threadIdx.x & 63;
  int r = blockIdx.x * 4 + (threadIdx.x >> 6);   // output row 0..63
  int c0 = lane * 4;
  float vre0 = (c0 + 0 == r) ? 1.f : 0.f, vim0 = 0.f;
  float vre1 = (c0 + 1 == r) ? 1.f : 0.f, vim1 = 0.f;
  float vre2 = (c0 + 2 == r) ? 1.f : 0.f, vim2 = 0.f;
  float vre3 = (c0 + 3 == r) ? 1.f : 0.f, vim3 = 0.f;

  P8 A, B;
  loadP8<TBL>(A, 31 * 8, lane, t4, t2, theta, phi);   // layers 255..248
  for (int it = 0; it < 16; ++it) {
    int bA = 31 - 2 * it;          // 8-layer block held in A
    int bB = bA - 1;
    loadP8<TBL>(B, bB * 8, lane, t4, t2, theta, phi);
#pragma unroll
    for (int k = 7; k >= 0; --k)   // l = bA*8+k descending; parity = k&1 (static)
      layer_step((k & 1) != 0, lane, A.qa[k], A.qb[k], A.cc[k],
                 vre0, vim0, vre1, vim1, vre2, vim2, vre3, vim3);
    if (it < 15)
      loadP8<TBL>(A, (bB - 1) * 8, lane, t4, t2, theta, phi);
#pragma unroll
    for (int k = 7; k >= 0; --k)
      layer_step((k & 1) != 0, lane, B.qa[k], B.qb[k], B.cc[k],
                 vre0, vim0, vre1, vim1, vre2, vim2, vre3, vim3);
  }

  // T[r][c] = Re(e^{i phi_out[r]} * V[r][c]) -> bf16
  float oph = outph[r];
  float co = cosf(oph), so = sinf(oph);
  bf16x4 o;
  o[0] = to_bf16(co * vre0 - so * vim0);
  o[1] = to_bf16(co * vre1 - so * vim1);
  o[2] = to_bf16(co * vre2 - so * vim2);
  o[3] = to_bf16(co * vre3 - so * vim3);
  *(bf16x4*)(Tb + r * 256 + c0) = o;
}

// ---------------------------------------------------------------------------
// Matmul: out[131072][64] = x[131072][256] @ T[64][256]^T, bf16 MFMA 16x16x32.
// Fragment layout (gfx950, verified via tr_b16/m156-m162 + m89 C/D):
//   A: m = lane&15, k = 4*(lane>>4)+i (i<4), +16 for i>=4
//   B: n = lane&15, k same pattern;  B[k][n] = T[n][k]
//   D: col(n) = lane&15, row(m) = 4*(lane>>4)+reg
// B (all 64x256, bf16 = 32KB) stays register-resident: 128 VGPR/lane.
// 512 blocks x 4 waves; each wave streams 4 m-tiles of 16 rows.
// ---------------------------------------------------------------------------
union FragB { bf16x8 v; uint2 u2[2]; };
union FragA { bf16x8 v; };

__global__ __launch_bounds__(256, 2) void olk_mm(
    const float* __restrict__ x, const __bf16* __restrict__ Tb,
    float* __restrict__ out) {
  int lane = threadIdx.x & 63;
  int gw = blockIdx.x * 4 + (threadIdx.x >> 6);   // 0..2047
  int l15 = lane & 15, lg = lane >> 4;

  FragB b[4][8];
#pragma unroll
  for (int nt = 0; nt < 4; ++nt) {
#pragma unroll
    for (int ks = 0; ks < 8; ++ks) {
      int row = nt * 16 + l15;
      int col = ks * 32 + 4 * lg;
      b[nt][ks].u2[0] = *(const uint2*)(Tb + row * 256 + col);
      b[nt][ks].u2[1] = *(const uint2*)(Tb + row * 256 + col + 16);
    }
  }

#pragma unroll 1
  for (int t = 0; t < 4; ++t) {
    int mt = gw * 4 + t;                          // m-tile 0..8191
    const float* xr = x + (size_t)(mt * 16 + l15) * 256 + 4 * lg;

    f32x4 acc[4];
#pragma unroll
    for (int nt = 0; nt < 4; ++nt) acc[nt] = (f32x4){0.f, 0.f, 0.f, 0.f};

    FragA a[8];
#pragma unroll
    for (int ks = 0; ks < 8; ++ks) {
      float4 lo = *(const float4*)(xr + ks * 32);
      float4 hi = *(const float4*)(xr + ks * 32 + 16);
      a[ks].v[0] = to_bf16(lo.x); a[ks].v[1] = to_bf16(lo.y);
      a[ks].v[2] = to_bf16(lo.z); a[ks].v[3] = to_bf16(lo.w);
      a[ks].v[4] = to_bf16(hi.x); a[ks].v[5] = to_bf16(hi.y);
      a[ks].v[6] = to_bf16(hi.z); a[ks].v[7] = to_bf16(hi.w);
    }

#pragma unroll
    for (int ks = 0; ks < 8; ++ks) {
#pragma unroll
      for (int nt = 0; nt < 4; ++nt)
        acc[nt] = __builtin_amdgcn_mfma_f32_16x16x32_bf16(
            a[ks].v, b[nt][ks].v, acc[nt], 0, 0, 0);
    }

    float* ob = out + (size_t)(mt * 16) * 64;
#pragma unroll
    for (int r = 0; r < 4; ++r) {
      int row = 4 * lg + r;
#pragma unroll
      for (int nt = 0; nt < 4; ++nt)   // r-then-nt: 256B contiguous per row
        ob[row * 64 + nt * 16 + l15] = acc[nt][r];
    }
  }
}

// ---------------------------------------------------------------------------
extern "C" void kernel_launch(void* const* d_in, const int* in_sizes, int n_in,
                              void* d_out, int out_size, void* d_ws, size_t ws_size,
                              hipStream_t stream) {
  const float* x     = (const float*)d_in[0];
  const float* theta = (const float*)d_in[1];
  const float* phi   = (const float*)d_in[2];
  const float* outph = (const float*)d_in[3];
  float* out = (float*)d_out;

  char* ws = (char*)d_ws;
  bool tbl = ws_size >= (size_t)(832 * 1024);
  float4* t4 = (float4*)ws;                       // 512 KB
  float2* t2 = (float2*)(ws + 512 * 1024);        // 256 KB
  __bf16* Tb = (__bf16*)(ws + (tbl ? 768 * 1024 : 0));  // 32 KB bf16 T

  if (tbl) {
    olk_params<<<128, 256, 0, stream>>>(theta, phi, t4, t2);
    olk_build<true><<<16, 256, 0, stream>>>(theta, phi, outph, t4, t2, Tb);
  } else {
    olk_build<false><<<16, 256, 0, stream>>>(theta, phi, outph, nullptr, nullptr, Tb);
  }
  olk_mm<<<512, 256, 0, stream>>>(x, Tb, out);
}